// Round 12
// baseline (78.121 us; speedup 1.0000x reference)
//
#include <hip/hip_runtime.h>
#include <math.h>

#define E_CNT 1999
#define N_PTS 2000
#define B_CNT 8
#define SEG 2048                           // X edges in [0,SEG), target edges in [SEG,2*SEG)
#define NTILES 16                          // 256-row tiles
#define NTP 136                            // upper-triangle tile pairs
#define NCH 2                              // 128-col chunks per 256-col tile
#define BLOCKS_PER_B (NTP*NCH)             // 272
#define TOTAL_BLOCKS (B_CNT*BLOCKS_PER_B)  // 2176
#define REP 5                              // diagnostic work multiplier
#define RSCALE 0.2f                        // 1/REP

#define HCEXP (-2.8853900817779268f)       // -2*log2(e)
#define SQRT_NEG2C 3.3972871f              // sqrt(8*log2(e))

typedef __attribute__((ext_vector_type(8))) _Float16 half8;
typedef __attribute__((ext_vector_type(4))) float f32x4;
typedef __attribute__((ext_vector_type(4))) int i32x4;

__device__ __forceinline__ half8 mk_frag(int lo, int hi) {
    i32x4 t; t[0] = lo; t[1] = hi; t[2] = 0; t[3] = 0;
    return __builtin_bit_cast(half8, t);
}

// Build the f16 edge record for slot of sample b:
//   halves [ s*cx, s*cy, s*cz, 0, u''x, u''y, u''z, 0 ],  s = sqrt(NEG2C),
//   u'' = (t/sqrt(l)) * exp2(HCEXP*|c|^2).   Pads are all-zero.
// When diagResp: returns l^2 + SRNF(X only) - selfterm (f32 recomputation of
// the MFMA path's self-pair from the ROUNDED f16 values).
__device__ __forceinline__ float edge_rec(
    const float* __restrict__ outp, const float* __restrict__ tgtp,
    const float* __restrict__ tmpl, int b, int slot, bool diagResp,
    i32x4& rec)
{
    float val = 0.f;
    bool isX = (slot < SEG);
    int e = isX ? slot : slot - SEG;
    if (e < E_CNT) {
        float ax, ay, az, bx, by, bz;
        if (isX) {
            const float* o0 = outp + ((size_t)b * N_PTS + e) * 3;
            const float* t0 = tmpl + (size_t)e * 3;
            ax = o0[0] + t0[0]; ay = o0[1] + t0[1]; az = o0[2] + t0[2];
            bx = o0[3] + t0[3]; by = o0[4] + t0[4]; bz = o0[5] + t0[5];
        } else {
            const float* g0 = tgtp + ((size_t)b * N_PTS + e) * 3;
            ax = g0[0]; ay = g0[1]; az = g0[2];
            bx = g0[3]; by = g0[4]; bz = g0[5];
        }
        float cx = 0.5f * (ax + bx), cy = 0.5f * (ay + by), cz = 0.5f * (az + bz);
        float tx = bx - ax, ty = by - ay, tz = bz - az;
        float l2 = tx * tx + ty * ty + tz * tz + 1e-12f;
        float l  = sqrtf(l2);
        float rs = rsqrtf(l);
        float f  = __builtin_amdgcn_exp2f(HCEXP * (cx * cx + cy * cy + cz * cz));
        float g  = rs * f;
        half8 hv;
        hv[0] = (_Float16)(SQRT_NEG2C * cx);
        hv[1] = (_Float16)(SQRT_NEG2C * cy);
        hv[2] = (_Float16)(SQRT_NEG2C * cz);
        hv[3] = (_Float16)0.f;
        hv[4] = (_Float16)(tx * g);
        hv[5] = (_Float16)(ty * g);
        hv[6] = (_Float16)(tz * g);
        hv[7] = (_Float16)0.f;
        rec = __builtin_bit_cast(i32x4, hv);
        if (diagResp) {
            float a0 = (float)hv[0], a1 = (float)hv[1], a2 = (float)hv[2];
            float d0 = (float)hv[4], d1 = (float)hv[5], d2 = (float)hv[6];
            float sarg = a0 * a0 + a1 * a1 + a2 * a2;
            float sdu  = d0 * d0 + d1 * d1 + d2 * d2;
            float self = __builtin_amdgcn_exp2f(sarg) * sdu * sdu;
            val = l * l - self;
            if (isX) {
                const float* t0 = tmpl + (size_t)e * 3;
                float txT = t0[3] - t0[0], tyT = t0[4] - t0[1], tzT = t0[5] - t0[2];
                float lT = sqrtf(txT * txT + tyT * tyT + tzT * tzT + 1e-12f);
                float rT = rsqrtf(lT);
                float dqx = tx * rs - txT * rT;     // q = t/sqrt(l)
                float dqy = ty * rs - tyT * rT;
                float dqz = tz * rs - tzT * rT;
                val += 1e-7f * (dqx * dqx + dqy * dqy + dqz * dqz);
            }
        }
    } else {
        i32x4 z; z[0] = 0; z[1] = 0; z[2] = 0; z[3] = 0;
        rec = z;
    }
    return val;
}

// DIAGNOSTIC build: K-loop repeated REP times (result scaled 1/REP) so the
// fused kernel's duration rises above the harness fills and its counters
// become visible.  A-fragments hoisted out of the loop (built once).
__global__ __launch_bounds__(256) void fused_kernel(
    const float* __restrict__ outp, const float* __restrict__ tgtp,
    const float* __restrict__ tmpl, float* __restrict__ part)
{
    __shared__ i32x4 sRec[385];    // [0,256) rows, [256,384) cols, [384] zero
    __shared__ float red[4];

    int id = blockIdx.x;
    int b  = id / BLOCKS_PER_B;
    int r  = id % BLOCKS_PER_B;
    int t  = r >> 1, ch = r & 1;
    int rt = 0, rem = t;
    while (rem >= NTILES - rt) { rem -= NTILES - rt; ++rt; }
    int ct = rt + rem;

    int tid = threadIdx.x, lane = tid & 63, w = tid >> 6;

    // stage: each thread one row record; threads <128 one col record.
    bool diagResp = (rt == ct) && ((tid >> 7) == ch);
    i32x4 rrec;
    float dval = edge_rec(outp, tgtp, tmpl, b, rt * 256 + tid, diagResp, rrec);
    sRec[tid] = rrec;
    if (tid < 128) {
        i32x4 crec;
        edge_rec(outp, tgtp, tmpl, b, ct * 256 + ch * 128 + tid, false, crec);
        sRec[256 + tid] = crec;
    }
    if (tid == 128) {
        i32x4 z; z[0] = 0; z[1] = 0; z[2] = 0; z[3] = 0;
        sRec[384] = z;
    }
    __syncthreads();

    int l15 = lane & 15;
    bool g0 = (lane < 16);            // lanes >=16 carry k>=8 (all zero)

    // A-side fragments for this wave's 4 row-tiles — built ONCE
    half8 aArg[4], aDu[4];
    #pragma unroll
    for (int q = 0; q < 4; ++q) {
        i32x4 ra = sRec[g0 ? ((w * 4 + q) * 16 + l15) : 384];
        aArg[q] = mk_frag(ra[0], ra[1]);
        aDu[q]  = mk_frag(ra[2], ra[3]);
    }

    f32x4 av = {0.f, 0.f, 0.f, 0.f};
    for (int rep = 0; rep < REP; ++rep) {
        #pragma unroll
        for (int ctile = 0; ctile < 8; ++ctile) {
            i32x4 rb = sRec[g0 ? (256 + ctile * 16 + l15) : 384];
            half8 bArg = mk_frag(rb[0], rb[1]);
            half8 bDu  = mk_frag(rb[2], rb[3]);
            #pragma unroll
            for (int q = 0; q < 4; ++q) {
                f32x4 zz = {0.f, 0.f, 0.f, 0.f};
                f32x4 dA = __builtin_amdgcn_mfma_f32_16x16x32_f16(aArg[q], bArg, zz, 0, 0, 0);
                f32x4 dD = __builtin_amdgcn_mfma_f32_16x16x32_f16(aDu[q],  bDu,  zz, 0, 0, 0);
                #pragma unroll
                for (int rr = 0; rr < 4; ++rr)
                    av[rr] = fmaf(__builtin_amdgcn_exp2f(dA[rr]), dD[rr] * dD[rr], av[rr]);
            }
        }
    }

    float sgn = (rt == ct) ? 1.f : (((rt < 8) == (ct < 8)) ? 2.f : -2.f);
    float thr = fmaf(sgn * RSCALE, (av[0] + av[1]) + (av[2] + av[3]), dval);
    for (int off = 32; off; off >>= 1) thr += __shfl_down(thr, off);
    if (lane == 0) red[w] = thr;
    __syncthreads();
    if (tid == 0)
        part[id] = (red[0] + red[1]) + (red[2] + red[3]);
}

__global__ __launch_bounds__(256) void final_kernel(
    const float* __restrict__ part, float* __restrict__ outv)
{
    float s = 0.f;
    for (int i = threadIdx.x; i < TOTAL_BLOCKS; i += 256) s += part[i];
    for (int off = 32; off; off >>= 1) s += __shfl_down(s, off);
    __shared__ float red[4];
    int lane = threadIdx.x & 63, wid = threadIdx.x >> 6;
    if (lane == 0) red[wid] = s;
    __syncthreads();
    if (threadIdx.x == 0)
        outv[0] = 0.125f * ((red[0] + red[1]) + (red[2] + red[3]));
}

extern "C" void kernel_launch(void* const* d_in, const int* in_sizes, int n_in,
                              void* d_out, int out_size, void* d_ws, size_t ws_size,
                              hipStream_t stream)
{
    const float* outp = (const float*)d_in[0];  // (8,2000,3) f32
    const float* tgtp = (const float*)d_in[1];  // (8,2000,3) f32
    const float* tmpl = (const float*)d_in[3];  // (2000,3) f32
    float* part = (float*)d_ws;                 // TOTAL_BLOCKS floats, all written each launch

    fused_kernel<<<TOTAL_BLOCKS, 256, 0, stream>>>(outp, tgtp, tmpl, part);
    final_kernel<<<1, 256, 0, stream>>>(part, (float*)d_out);
}

// Round 13
// 30.102 us; speedup vs baseline: 2.5952x; 2.5952x over previous
//
#include <hip/hip_runtime.h>
#include <math.h>

#define E_CNT 1999
#define N_PTS 2000
#define B_CNT 8
#define SEG 2048                           // X edges in [0,SEG), target edges in [SEG,2*SEG)
#define MPAD (2*SEG)                       // 4096
#define NTILES 16                          // 256-row tiles
#define NTP 136                            // upper-triangle tile pairs
#define NCH 2                              // 128-col chunks per 256-col tile
#define BLOCKS_PER_B (NTP*NCH)             // 272
#define TOTAL_BLOCKS (B_CNT*BLOCKS_PER_B)  // 2176
#define PRE_BLOCKS  (B_CNT*16)             // 128
#define NPART (TOTAL_BLOCKS + PRE_BLOCKS)  // 2304

#define HCEXP (-2.8853900817779268f)       // -2*log2(e)
#define SQRT_NEG2C 3.3972871f              // sqrt(8*log2(e))

typedef __attribute__((ext_vector_type(8))) _Float16 half8;
typedef __attribute__((ext_vector_type(4))) float f32x4;
typedef __attribute__((ext_vector_type(4))) int i32x4;

__device__ __forceinline__ half8 mk_frag(int lo, int hi) {
    i32x4 t; t[0] = lo; t[1] = hi; t[2] = 0; t[3] = 0;
    return __builtin_bit_cast(half8, t);
}

// Precompute the f16 edge record for every slot of every sample (ONCE):
//   halves [ s*cx, s*cy, s*cz, 0, u''x, u''y, u''z, 0 ],  s = sqrt(NEG2C),
//   u'' = (t/sqrt(l)) * exp2(HCEXP*|c|^2).  Pads all-zero.
// Also accumulates per-edge diag value: l^2 + SRNF(X) - selfterm, where
// selfterm is the f32 recomputation (from the ROUNDED f16 values) of what
// the MFMA path produces for the self-pair (i,i) — counted exactly once
// per edge here, cancelling the full-weight in-tile diagonal.
__global__ __launch_bounds__(256) void pre_kernel(
    const float* __restrict__ outp, const float* __restrict__ tgtp,
    const float* __restrict__ tmpl, i32x4* __restrict__ recs,
    float* __restrict__ part)
{
    int b = blockIdx.x >> 4;
    int p = ((blockIdx.x & 15) << 8) + threadIdx.x;   // 0..4095

    float val = 0.f;
    i32x4 rec; rec[0] = 0; rec[1] = 0; rec[2] = 0; rec[3] = 0;

    bool isX = (p < SEG);
    int e = isX ? p : p - SEG;
    if (e < E_CNT) {
        float ax, ay, az, bx, by, bz;
        if (isX) {
            const float* o0 = outp + ((size_t)b * N_PTS + e) * 3;
            const float* t0 = tmpl + (size_t)e * 3;
            ax = o0[0] + t0[0]; ay = o0[1] + t0[1]; az = o0[2] + t0[2];
            bx = o0[3] + t0[3]; by = o0[4] + t0[4]; bz = o0[5] + t0[5];
        } else {
            const float* g0 = tgtp + ((size_t)b * N_PTS + e) * 3;
            ax = g0[0]; ay = g0[1]; az = g0[2];
            bx = g0[3]; by = g0[4]; bz = g0[5];
        }
        float cx = 0.5f * (ax + bx), cy = 0.5f * (ay + by), cz = 0.5f * (az + bz);
        float tx = bx - ax, ty = by - ay, tz = bz - az;
        float l2 = tx * tx + ty * ty + tz * tz + 1e-12f;
        float l  = sqrtf(l2);
        float rs = rsqrtf(l);
        float f  = __builtin_amdgcn_exp2f(HCEXP * (cx * cx + cy * cy + cz * cz));
        float g  = rs * f;
        half8 hv;
        hv[0] = (_Float16)(SQRT_NEG2C * cx);
        hv[1] = (_Float16)(SQRT_NEG2C * cy);
        hv[2] = (_Float16)(SQRT_NEG2C * cz);
        hv[3] = (_Float16)0.f;
        hv[4] = (_Float16)(tx * g);
        hv[5] = (_Float16)(ty * g);
        hv[6] = (_Float16)(tz * g);
        hv[7] = (_Float16)0.f;
        rec = __builtin_bit_cast(i32x4, hv);

        float a0 = (float)hv[0], a1 = (float)hv[1], a2 = (float)hv[2];
        float d0 = (float)hv[4], d1 = (float)hv[5], d2 = (float)hv[6];
        float sarg = a0 * a0 + a1 * a1 + a2 * a2;
        float sdu  = d0 * d0 + d1 * d1 + d2 * d2;
        float self = __builtin_amdgcn_exp2f(sarg) * sdu * sdu;
        val = l * l - self;
        if (isX) {
            const float* t0 = tmpl + (size_t)e * 3;
            float txT = t0[3] - t0[0], tyT = t0[4] - t0[1], tzT = t0[5] - t0[2];
            float lT = sqrtf(txT * txT + tyT * tyT + tzT * tzT + 1e-12f);
            float rT = rsqrtf(lT);
            float dqx = tx * rs - txT * rT;     // q = t/sqrt(l)
            float dqy = ty * rs - tyT * rT;
            float dqz = tz * rs - tzT * rT;
            val += 1e-7f * (dqx * dqx + dqy * dqy + dqz * dqz);
        }
    }
    recs[(size_t)b * MPAD + p] = rec;

    for (int off = 32; off; off >>= 1) val += __shfl_down(val, off);
    __shared__ float red[4];
    int lane = threadIdx.x & 63, wid = threadIdx.x >> 6;
    if (lane == 0) red[wid] = val;
    __syncthreads();
    if (threadIdx.x == 0)
        part[TOTAL_BLOCKS + blockIdx.x] = (red[0] + red[1]) + (red[2] + red[3]);
}

// MFMA pair kernel, staging = coalesced 16B record loads (no edge math).
// Block = 256 rows x 128 cols; 16x16 tiles via two mfma_f32_16x16x32_f16;
// diag tile-pairs at weight 1 (self-pairs pre-cancelled in pre_kernel),
// off-diag x2, cross-segment negative.  No atomics.
__global__ __launch_bounds__(256) void pair_kernel(
    const i32x4* __restrict__ recs, float* __restrict__ part)
{
    __shared__ i32x4 sRec[385];    // [0,256) rows, [256,384) cols, [384] zero
    __shared__ float red[4];

    int id = blockIdx.x;
    int b  = id / BLOCKS_PER_B;
    int r  = id % BLOCKS_PER_B;
    int t  = r >> 1, ch = r & 1;
    int rt = 0, rem = t;
    while (rem >= NTILES - rt) { rem -= NTILES - rt; ++rt; }
    int ct = rt + rem;

    int tid = threadIdx.x, lane = tid & 63, w = tid >> 6;
    const i32x4* __restrict__ rb8 = recs + (size_t)b * MPAD;

    sRec[tid] = rb8[rt * 256 + tid];
    if (tid < 128)
        sRec[256 + tid] = rb8[ct * 256 + ch * 128 + tid];
    if (tid == 128) {
        i32x4 z; z[0] = 0; z[1] = 0; z[2] = 0; z[3] = 0;
        sRec[384] = z;
    }
    __syncthreads();

    int l15 = lane & 15;
    bool g0 = (lane < 16);            // lanes >=16 carry k>=8 (all zero)

    // A-side fragments for this wave's 4 row-tiles — built once
    half8 aArg[4], aDu[4];
    #pragma unroll
    for (int q = 0; q < 4; ++q) {
        i32x4 ra = sRec[g0 ? ((w * 4 + q) * 16 + l15) : 384];
        aArg[q] = mk_frag(ra[0], ra[1]);
        aDu[q]  = mk_frag(ra[2], ra[3]);
    }

    f32x4 av = {0.f, 0.f, 0.f, 0.f};
    #pragma unroll
    for (int ctile = 0; ctile < 8; ++ctile) {
        i32x4 rb = sRec[g0 ? (256 + ctile * 16 + l15) : 384];
        half8 bArg = mk_frag(rb[0], rb[1]);
        half8 bDu  = mk_frag(rb[2], rb[3]);
        #pragma unroll
        for (int q = 0; q < 4; ++q) {
            f32x4 zz = {0.f, 0.f, 0.f, 0.f};
            f32x4 dA = __builtin_amdgcn_mfma_f32_16x16x32_f16(aArg[q], bArg, zz, 0, 0, 0);
            f32x4 dD = __builtin_amdgcn_mfma_f32_16x16x32_f16(aDu[q],  bDu,  zz, 0, 0, 0);
            #pragma unroll
            for (int rr = 0; rr < 4; ++rr)
                av[rr] = fmaf(__builtin_amdgcn_exp2f(dA[rr]), dD[rr] * dD[rr], av[rr]);
        }
    }

    float sgn = (rt == ct) ? 1.f : (((rt < 8) == (ct < 8)) ? 2.f : -2.f);
    float thr = sgn * ((av[0] + av[1]) + (av[2] + av[3]));
    for (int off = 32; off; off >>= 1) thr += __shfl_down(thr, off);
    if (lane == 0) red[w] = thr;
    __syncthreads();
    if (tid == 0)
        part[id] = (red[0] + red[1]) + (red[2] + red[3]);
}

__global__ __launch_bounds__(256) void final_kernel(
    const float* __restrict__ part, float* __restrict__ outv)
{
    float s = 0.f;
    for (int i = threadIdx.x; i < NPART; i += 256) s += part[i];
    for (int off = 32; off; off >>= 1) s += __shfl_down(s, off);
    __shared__ float red[4];
    int lane = threadIdx.x & 63, wid = threadIdx.x >> 6;
    if (lane == 0) red[wid] = s;
    __syncthreads();
    if (threadIdx.x == 0)
        outv[0] = 0.125f * ((red[0] + red[1]) + (red[2] + red[3]));
}

extern "C" void kernel_launch(void* const* d_in, const int* in_sizes, int n_in,
                              void* d_out, int out_size, void* d_ws, size_t ws_size,
                              hipStream_t stream)
{
    const float* outp = (const float*)d_in[0];  // (8,2000,3) f32
    const float* tgtp = (const float*)d_in[1];  // (8,2000,3) f32
    const float* tmpl = (const float*)d_in[3];  // (2000,3) f32
    float* part = (float*)d_ws;                              // NPART floats
    i32x4* recs = (i32x4*)((char*)d_ws + 16384);             // 512 KiB records

    pre_kernel<<<PRE_BLOCKS, 256, 0, stream>>>(outp, tgtp, tmpl, recs, part);
    pair_kernel<<<TOTAL_BLOCKS, 256, 0, stream>>>(recs, part);
    final_kernel<<<1, 256, 0, stream>>>(part, (float*)d_out);
}

// Round 14
// 26.273 us; speedup vs baseline: 2.9735x; 1.1458x over previous
//
#include <hip/hip_runtime.h>
#include <math.h>

#define E_CNT 1999
#define N_PTS 2000
#define B_CNT 8
#define SEG 2048                           // X edges in [0,SEG), target edges in [SEG,2*SEG)
#define NTILES 16                          // 256-row tiles
#define NTP 136                            // upper-triangle tile pairs
#define TOTAL_BLOCKS (B_CNT*NTP)           // 1088: one block per (sample, tile-pair)

#define HCEXP (-2.8853900817779268f)       // -2*log2(e)
#define SQRT_NEG2C 3.3972871f              // sqrt(8*log2(e))

typedef __attribute__((ext_vector_type(8))) _Float16 half8;
typedef __attribute__((ext_vector_type(4))) float f32x4;
typedef __attribute__((ext_vector_type(4))) int i32x4;

__device__ __forceinline__ half8 mk_frag(int lo, int hi) {
    i32x4 t; t[0] = lo; t[1] = hi; t[2] = 0; t[3] = 0;
    return __builtin_bit_cast(half8, t);
}

// f16 edge record for slot of sample b:
//   halves [ s*cx, s*cy, s*cz, 0, u''x, u''y, u''z, 0 ],  s = sqrt(NEG2C),
//   u'' = (t/sqrt(l)) * exp2(HCEXP*|c|^2).  Pads all-zero.
// diagResp: also return l^2 + SRNF(X) - selfterm (f32 recomputation of the
// MFMA self-pair from ROUNDED f16 values — cancels the in-tile diagonal).
__device__ __forceinline__ float edge_rec(
    const float* __restrict__ outp, const float* __restrict__ tgtp,
    const float* __restrict__ tmpl, int b, int slot, bool diagResp,
    i32x4& rec)
{
    float val = 0.f;
    bool isX = (slot < SEG);
    int e = isX ? slot : slot - SEG;
    if (e < E_CNT) {
        float ax, ay, az, bx, by, bz;
        if (isX) {
            const float* o0 = outp + ((size_t)b * N_PTS + e) * 3;
            const float* t0 = tmpl + (size_t)e * 3;
            ax = o0[0] + t0[0]; ay = o0[1] + t0[1]; az = o0[2] + t0[2];
            bx = o0[3] + t0[3]; by = o0[4] + t0[4]; bz = o0[5] + t0[5];
        } else {
            const float* g0 = tgtp + ((size_t)b * N_PTS + e) * 3;
            ax = g0[0]; ay = g0[1]; az = g0[2];
            bx = g0[3]; by = g0[4]; bz = g0[5];
        }
        float cx = 0.5f * (ax + bx), cy = 0.5f * (ay + by), cz = 0.5f * (az + bz);
        float tx = bx - ax, ty = by - ay, tz = bz - az;
        float l2 = tx * tx + ty * ty + tz * tz + 1e-12f;
        float l  = sqrtf(l2);
        float rs = rsqrtf(l);
        float f  = __builtin_amdgcn_exp2f(HCEXP * (cx * cx + cy * cy + cz * cz));
        float g  = rs * f;
        half8 hv;
        hv[0] = (_Float16)(SQRT_NEG2C * cx);
        hv[1] = (_Float16)(SQRT_NEG2C * cy);
        hv[2] = (_Float16)(SQRT_NEG2C * cz);
        hv[3] = (_Float16)0.f;
        hv[4] = (_Float16)(tx * g);
        hv[5] = (_Float16)(ty * g);
        hv[6] = (_Float16)(tz * g);
        hv[7] = (_Float16)0.f;
        rec = __builtin_bit_cast(i32x4, hv);
        if (diagResp) {
            float a0 = (float)hv[0], a1 = (float)hv[1], a2 = (float)hv[2];
            float d0 = (float)hv[4], d1 = (float)hv[5], d2 = (float)hv[6];
            float sarg = a0 * a0 + a1 * a1 + a2 * a2;
            float sdu  = d0 * d0 + d1 * d1 + d2 * d2;
            float self = __builtin_amdgcn_exp2f(sarg) * sdu * sdu;
            val = l * l - self;
            if (isX) {
                const float* t0 = tmpl + (size_t)e * 3;
                float txT = t0[3] - t0[0], tyT = t0[4] - t0[1], tzT = t0[5] - t0[2];
                float lT = sqrtf(txT * txT + tyT * tyT + tzT * tzT + 1e-12f);
                float rT = rsqrtf(lT);
                float dqx = tx * rs - txT * rT;     // q = t/sqrt(l)
                float dqy = ty * rs - tyT * rT;
                float dqz = tz * rs - tzT * rT;
                val += 1e-7f * (dqx * dqx + dqy * dqy + dqz * dqz);
            }
        }
    } else {
        i32x4 z; z[0] = 0; z[1] = 0; z[2] = 0; z[3] = 0;
        rec = z;
    }
    return val;
}

// One block per (sample, tile-pair): 256 rows x 256 cols — 2x the K-loop of
// the R11 structure, same per-block fixed cost, half the blocks.  Staging
// fused in (R12/R13 showed staging mode is perf-neutral; saves a launch).
// Diag tile-pairs (rt==ct, 16/sample) stage each row slot exactly once and
// carry the diag/SRNF/self-cancel term; weight 1.  Off-diag weight +-2.
__global__ __launch_bounds__(256) void fused_kernel(
    const float* __restrict__ outp, const float* __restrict__ tgtp,
    const float* __restrict__ tmpl, float* __restrict__ part)
{
    __shared__ i32x4 sRec[513];    // [0,256) rows, [256,512) cols, [512] zero
    __shared__ float red[4];

    int id = blockIdx.x;
    int b  = id / NTP;
    int t  = id % NTP;
    int rt = 0, rem = t;
    while (rem >= NTILES - rt) { rem -= NTILES - rt; ++rt; }
    int ct = rt + rem;

    int tid = threadIdx.x, lane = tid & 63, w = tid >> 6;
    bool isDiag = (rt == ct);

    // stage: each thread one row record (+ col record if off-diag)
    i32x4 rrec;
    float dval = edge_rec(outp, tgtp, tmpl, b, rt * 256 + tid, isDiag, rrec);
    sRec[tid] = rrec;
    if (isDiag) {
        sRec[256 + tid] = rrec;
    } else {
        i32x4 crec;
        edge_rec(outp, tgtp, tmpl, b, ct * 256 + tid, false, crec);
        sRec[256 + tid] = crec;
    }
    if (tid == 0) {
        i32x4 z; z[0] = 0; z[1] = 0; z[2] = 0; z[3] = 0;
        sRec[512] = z;
    }
    __syncthreads();

    int l15 = lane & 15;
    bool g0 = (lane < 16);            // lanes >=16 carry k>=8 (all zero)

    // A-side fragments for this wave's 4 row-tiles — built once
    half8 aArg[4], aDu[4];
    #pragma unroll
    for (int q = 0; q < 4; ++q) {
        i32x4 ra = sRec[g0 ? ((w * 4 + q) * 16 + l15) : 512];
        aArg[q] = mk_frag(ra[0], ra[1]);
        aDu[q]  = mk_frag(ra[2], ra[3]);
    }

    f32x4 av = {0.f, 0.f, 0.f, 0.f};
    #pragma unroll 2
    for (int ctile = 0; ctile < 16; ++ctile) {
        i32x4 rb = sRec[g0 ? (256 + ctile * 16 + l15) : 512];
        half8 bArg = mk_frag(rb[0], rb[1]);
        half8 bDu  = mk_frag(rb[2], rb[3]);
        #pragma unroll
        for (int q = 0; q < 4; ++q) {
            f32x4 zz = {0.f, 0.f, 0.f, 0.f};
            f32x4 dA = __builtin_amdgcn_mfma_f32_16x16x32_f16(aArg[q], bArg, zz, 0, 0, 0);
            f32x4 dD = __builtin_amdgcn_mfma_f32_16x16x32_f16(aDu[q],  bDu,  zz, 0, 0, 0);
            #pragma unroll
            for (int rr = 0; rr < 4; ++rr)
                av[rr] = fmaf(__builtin_amdgcn_exp2f(dA[rr]), dD[rr] * dD[rr], av[rr]);
        }
    }

    // diag tile-pair x1 (self-pairs cancelled via selfterm in dval);
    // off-diag x2; cross-segment negative.
    float sgn = isDiag ? 1.f : (((rt < 8) == (ct < 8)) ? 2.f : -2.f);
    float thr = fmaf(sgn, (av[0] + av[1]) + (av[2] + av[3]), dval);
    for (int off = 32; off; off >>= 1) thr += __shfl_down(thr, off);
    if (lane == 0) red[w] = thr;
    __syncthreads();
    if (tid == 0)
        part[id] = (red[0] + red[1]) + (red[2] + red[3]);
}

__global__ __launch_bounds__(256) void final_kernel(
    const float* __restrict__ part, float* __restrict__ outv)
{
    float s = 0.f;
    for (int i = threadIdx.x; i < TOTAL_BLOCKS; i += 256) s += part[i];
    for (int off = 32; off; off >>= 1) s += __shfl_down(s, off);
    __shared__ float red[4];
    int lane = threadIdx.x & 63, wid = threadIdx.x >> 6;
    if (lane == 0) red[wid] = s;
    __syncthreads();
    if (threadIdx.x == 0)
        outv[0] = 0.125f * ((red[0] + red[1]) + (red[2] + red[3]));
}

extern "C" void kernel_launch(void* const* d_in, const int* in_sizes, int n_in,
                              void* d_out, int out_size, void* d_ws, size_t ws_size,
                              hipStream_t stream)
{
    const float* outp = (const float*)d_in[0];  // (8,2000,3) f32
    const float* tgtp = (const float*)d_in[1];  // (8,2000,3) f32
    const float* tmpl = (const float*)d_in[3];  // (2000,3) f32
    float* part = (float*)d_ws;                 // TOTAL_BLOCKS floats, all written each launch

    fused_kernel<<<TOTAL_BLOCKS, 256, 0, stream>>>(outp, tgtp, tmpl, part);
    final_kernel<<<1, 256, 0, stream>>>(part, (float*)d_out);
}